// Round 5
// baseline (1040.944 us; speedup 1.0000x reference)
//
#include <hip/hip_runtime.h>

// LightGCN R8: attack spmm miss-concurrency (Little's-law bound).
// R7 evidence: spmm 3x219us = 63% of total; 45% HBM, VALUBusy 25%,
// occupancy 79%; R6's full col-sort gave ~no spmm gain -> not hit-rate
// bound; ~0.18 line-misses/cy/CU at ~250cy latency needs ~45 outstanding
// misses/CU = MSHR edge. Fix: 4 independent gathers in flight per wave
// iteration + int4 paired edge loads (halves edge-load instrs/lines).
// Build pipeline (coarse-bucket multisplit + per-bucket counting sort)
// unchanged from R7.

constexpr int N_USERS_C = 100000;
constexpr int N_NODES_C = 300000;
constexpr int NNZ_C     = 9600000;
constexpr int DIM       = 64;
constexpr int TOT4      = N_NODES_C * DIM / 4;   // 4,800,000 float4
constexpr int USER4     = N_USERS_C * DIM / 4;   // 1,600,000

constexpr int BKT_SHIFT = 9;
constexpr int BKT_ROWS  = 512;
constexpr int NBKT      = (N_NODES_C + BKT_ROWS - 1) / BKT_ROWS; // 586
constexpr int CPAD      = 16;               // ints per counter (cacheline pad)
constexpr int COL_MASK  = (1 << 19) - 1;    // col < 2^19; rl in bits 19..27

// RNE f32 -> bf16 pair packed into one uint (elem a in low ushort)
__device__ inline unsigned pack_bf16(float a, float b) {
    unsigned ua = __float_as_uint(a);
    unsigned ub = __float_as_uint(b);
    ua += 0x7fffu + ((ua >> 16) & 1u);
    ub += 0x7fffu + ((ub >> 16) & 1u);
    return (ua >> 16) | (ub & 0xffff0000u);
}
__device__ inline float bf_lo(unsigned w) { return __uint_as_float(w << 16); }
__device__ inline float bf_hi(unsigned w) { return __uint_as_float(w & 0xffff0000u); }

// ---------------- init: bf16 table only ----------------

__global__ void __launch_bounds__(256) init_concat_bf16(
    const float4* __restrict__ user4,
    const float4* __restrict__ item4,
    uint2*  __restrict__ xb)     // TOT4 uint2 (4 bf16 each)
{
    int i = blockIdx.x * 256 + threadIdx.x;
    if (i >= TOT4) return;
    float4 v = (i < USER4) ? user4[i] : item4[i - USER4];
    xb[i] = make_uint2(pack_bf16(v.x, v.y), pack_bf16(v.z, v.w));
}

// ---------------- bucket build ----------------

// LDS-aggregated histogram: 256 blocks x contiguous chunks.
__global__ void __launch_bounds__(1024) bucket_hist_lds(
    const int* __restrict__ rows, int* __restrict__ countsP)
{
    __shared__ int h[NBKT];
    for (int i = threadIdx.x; i < NBKT; i += 1024) h[i] = 0;
    __syncthreads();
    int per = (NNZ_C + gridDim.x - 1) / gridDim.x;
    int s = blockIdx.x * per;
    int e = min(s + per, NNZ_C);
    for (int i = s + (int)threadIdx.x; i < e; i += 1024)
        atomicAdd(&h[rows[i] >> BKT_SHIFT], 1);
    __syncthreads();
    for (int i = threadIdx.x; i < NBKT; i += 1024) {
        int c = h[i];
        if (c) atomicAdd(&countsP[i * CPAD], c);
    }
}

// NBKT (586) <= 1024: one bucket per thread, single Hillis-Steele scan.
__global__ void __launch_bounds__(1024) bucket_scan(
    const int* __restrict__ countsP,
    int* __restrict__ bstart,        // NBKT+1
    int* __restrict__ cursorP)
{
    __shared__ int lds[1024];
    int t = threadIdx.x;
    int v = (t < NBKT) ? countsP[t * CPAD] : 0;
    lds[t] = v;
    __syncthreads();
    for (int off = 1; off < 1024; off <<= 1) {
        int x = (t >= off) ? lds[t - off] : 0;
        __syncthreads();
        lds[t] += x;
        __syncthreads();
    }
    int excl = lds[t] - v;
    if (t < NBKT) {
        bstart[t] = excl;
        cursorP[t * CPAD] = excl;
    }
    if (t == 1023) bstart[NBKT] = lds[1023];
}

// LDS-staged multisplit partition into 586 coarse buckets.
constexpr int STAGE_T   = 6144;            // edges per tile
constexpr int STAGE_EPT = STAGE_T / 1024;  // 6 edges per thread

__global__ void __launch_bounds__(1024) bin_stage(
    const int* __restrict__ rows, const int* __restrict__ cols,
    const float* __restrict__ vals, int* __restrict__ cursorP,
    int2* __restrict__ binned)
{
    __shared__ int2 stage[STAGE_T];              // 48 KB
    __shared__ unsigned short destB[STAGE_T];    // 12 KB
    __shared__ int hist[NBKT];                   // 2.3 KB (counts, then delta)
    __shared__ int basep[NBKT];                  // 2.3 KB (tile-local excl scan)
    __shared__ int part[16];                     // wave partials

    int t  = threadIdx.x;
    int e0 = blockIdx.x * STAGE_T;
    int cnt = min(STAGE_T, NNZ_C - e0);

    for (int i = t; i < NBKT; i += 1024) hist[i] = 0;
    __syncthreads();

    // load + local rank via atomic-return
    int  myB[STAGE_EPT];
    int  myR[STAGE_EPT];
    int2 myP[STAGE_EPT];
    #pragma unroll
    for (int j = 0; j < STAGE_EPT; ++j) {
        int i = t + j * 1024;
        myB[j] = -1;
        if (i < cnt) {
            int r = rows[e0 + i];
            int b = r >> BKT_SHIFT;
            myB[j] = b;
            myP[j] = make_int2(((r & (BKT_ROWS - 1)) << 19) | cols[e0 + i],
                               __float_as_int(vals[e0 + i]));
            myR[j] = atomicAdd(&hist[b], 1);
        }
    }
    __syncthreads();

    // exclusive scan of hist into basep (1 entry/thread, shfl wave scan)
    int v0 = (t < NBKT) ? hist[t] : 0;

    int lane = t & 63, wid = t >> 6;
    int x = v0;
    #pragma unroll
    for (int d = 1; d < 64; d <<= 1) {
        int y = __shfl_up(x, d);
        if (lane >= d) x += y;
    }
    if (lane == 63) part[wid] = x;
    __syncthreads();
    if (wid == 0 && lane < 16) {
        int w = part[lane];
        #pragma unroll
        for (int d = 1; d < 16; d <<= 1) {
            int y = __shfl_up(w, d);
            if (lane >= d) w += y;
        }
        part[lane] = w;
    }
    __syncthreads();
    int excl = ((wid == 0) ? 0 : part[wid - 1]) + (x - v0);
    if (t < NBKT) basep[t] = excl;
    __syncthreads();

    // reserve global ranges: hist[b] := gbase_b - lstart_b (delta)
    for (int i = t; i < NBKT; i += 1024) {
        int c = hist[i];
        hist[i] = (c > 0) ? (atomicAdd(&cursorP[i * CPAD], c) - basep[i]) : 0;
    }
    // permute payloads bucket-contiguous in LDS
    #pragma unroll
    for (int j = 0; j < STAGE_EPT; ++j) {
        if (myB[j] >= 0) {
            int q = basep[myB[j]] + myR[j];
            stage[q] = myP[j];
            destB[q] = (unsigned short)myB[j];
        }
    }
    __syncthreads();

    // coalesced-with-gaps output: ~10-edge (84B) runs per bucket
    #pragma unroll
    for (int j = 0; j < STAGE_EPT; ++j) {
        int p = t + j * 1024;
        if (p < cnt) {
            int b = destB[p];
            binned[hist[b] + p] = stage[p];
        }
    }
}

// per-coarse-bucket counting sort -> final CSR (binned2) + rowStart.
// One block per 512-row segment (~131 KB of edges): pass1 hist, pass2
// scatter. Second pass and all writes are L2-local -> no write amp.
__global__ void __launch_bounds__(1024) sort_bucket(
    const int2* __restrict__ binned,
    const int*  __restrict__ bstart,
    int2* __restrict__ binned2,
    int*  __restrict__ rowStart)    // N_NODES_C + 1
{
    __shared__ int hist[BKT_ROWS];
    __shared__ int scanb[BKT_ROWS];
    __shared__ int cur[BKT_ROWS];

    int b = blockIdx.x;
    int t = threadIdx.x;
    int s = bstart[b];
    int n = bstart[b + 1] - s;

    if (t < BKT_ROWS) hist[t] = 0;
    __syncthreads();

    for (int i = t; i < n; i += 1024)
        atomicAdd(&hist[binned[s + i].x >> 19], 1);
    __syncthreads();

    if (t < BKT_ROWS) scanb[t] = hist[t];
    __syncthreads();
    for (int off = 1; off < BKT_ROWS; off <<= 1) {
        int v = (t < BKT_ROWS && t >= off) ? scanb[t - off] : 0;
        __syncthreads();
        if (t < BKT_ROWS) scanb[t] += v;
        __syncthreads();
    }

    int rowBase = b << BKT_SHIFT;
    int nRows = min(BKT_ROWS, N_NODES_C - rowBase);
    if (t < BKT_ROWS) {
        int st = (t == 0) ? 0 : scanb[t - 1];
        cur[t] = st;
        if (t < nRows) rowStart[rowBase + t] = s + st;
    }
    if (b == 0 && t == 0) rowStart[N_NODES_C] = NNZ_C;
    __syncthreads();

    for (int i = t; i < n; i += 1024) {
        int2 p = binned[s + i];
        int rl = p.x >> 19;
        int pos = atomicAdd(&cur[rl], 1);
        binned2[s + pos] = make_int2(p.x & COL_MASK, p.y);
    }
}

// ---------------- pull SpMM, bf16 gathers, fused acc ----------------
// 8 lanes per row; lane q owns dims [8q, 8q+8). One uint4 = 8 bf16 per gather.
// 4-deep gather pipeline + int4 paired edge loads (miss concurrency).
// layer0: read x0 from uemb/iemb (init never writes acc).
__global__ void __launch_bounds__(256) spmm_pull_bf16(
    const int2* __restrict__ edges,
    const int*  __restrict__ rowStart,
    const uint4* __restrict__ xb,      // bf16 table: 8 uint4 per row
    uint4* __restrict__ xb_next,       // next layer's bf16 table
    float4* __restrict__ acc,          // d_out, f32
    const float4* __restrict__ x0u,
    const float4* __restrict__ x0i,
    int layer0,
    float scale)
{
    int tid = blockIdx.x * 256 + threadIdx.x;
    int row = tid >> 3;
    if (row >= N_NODES_C) return;
    int q = tid & 7;

    int s = rowStart[row];
    int e = rowStart[row + 1];

    float y0 = 0.f, y1 = 0.f, y2 = 0.f, y3 = 0.f;
    float y4 = 0.f, y5 = 0.f, y6 = 0.f, y7 = 0.f;

    const uint4* xq = xb + q;

    int i = s;
    // peel to even index so int4 (2-edge) loads are 16B-aligned
    if ((i & 1) && i < e) {
        int2 p = edges[i];
        uint4 u = xq[(size_t)p.x * 8];
        float v = __int_as_float(p.y);
        y0 += v * bf_lo(u.x); y1 += v * bf_hi(u.x);
        y2 += v * bf_lo(u.y); y3 += v * bf_hi(u.y);
        y4 += v * bf_lo(u.z); y5 += v * bf_hi(u.z);
        y6 += v * bf_lo(u.w); y7 += v * bf_hi(u.w);
        ++i;
    }
    // main: 4 edges per iteration, 2 int4 edge loads + 4 independent gathers
    for (; i + 3 < e; i += 4) {
        int4 qa = *reinterpret_cast<const int4*>(edges + i);       // e0,e1
        int4 qb = *reinterpret_cast<const int4*>(edges + i + 2);   // e2,e3
        uint4 u0 = xq[(size_t)qa.x * 8];
        uint4 u1 = xq[(size_t)qa.z * 8];
        uint4 u2 = xq[(size_t)qb.x * 8];
        uint4 u3 = xq[(size_t)qb.z * 8];
        float v0 = __int_as_float(qa.y);
        float v1 = __int_as_float(qa.w);
        float v2 = __int_as_float(qb.y);
        float v3 = __int_as_float(qb.w);
        y0 += v0 * bf_lo(u0.x); y1 += v0 * bf_hi(u0.x);
        y2 += v0 * bf_lo(u0.y); y3 += v0 * bf_hi(u0.y);
        y4 += v0 * bf_lo(u0.z); y5 += v0 * bf_hi(u0.z);
        y6 += v0 * bf_lo(u0.w); y7 += v0 * bf_hi(u0.w);
        y0 += v1 * bf_lo(u1.x); y1 += v1 * bf_hi(u1.x);
        y2 += v1 * bf_lo(u1.y); y3 += v1 * bf_hi(u1.y);
        y4 += v1 * bf_lo(u1.z); y5 += v1 * bf_hi(u1.z);
        y6 += v1 * bf_lo(u1.w); y7 += v1 * bf_hi(u1.w);
        y0 += v2 * bf_lo(u2.x); y1 += v2 * bf_hi(u2.x);
        y2 += v2 * bf_lo(u2.y); y3 += v2 * bf_hi(u2.y);
        y4 += v2 * bf_lo(u2.z); y5 += v2 * bf_hi(u2.z);
        y6 += v2 * bf_lo(u2.w); y7 += v2 * bf_hi(u2.w);
        y0 += v3 * bf_lo(u3.x); y1 += v3 * bf_hi(u3.x);
        y2 += v3 * bf_lo(u3.y); y3 += v3 * bf_hi(u3.y);
        y4 += v3 * bf_lo(u3.z); y5 += v3 * bf_hi(u3.z);
        y6 += v3 * bf_lo(u3.w); y7 += v3 * bf_hi(u3.w);
    }
    // tail (0..3 edges)
    for (; i < e; ++i) {
        int2 p = edges[i];
        uint4 u = xq[(size_t)p.x * 8];
        float v = __int_as_float(p.y);
        y0 += v * bf_lo(u.x); y1 += v * bf_hi(u.x);
        y2 += v * bf_lo(u.y); y3 += v * bf_hi(u.y);
        y4 += v * bf_lo(u.z); y5 += v * bf_hi(u.z);
        y6 += v * bf_lo(u.w); y7 += v * bf_hi(u.w);
    }

    // next-layer bf16 table = raw y (pre-scale)
    uint4 o;
    o.x = pack_bf16(y0, y1);
    o.y = pack_bf16(y2, y3);
    o.z = pack_bf16(y4, y5);
    o.w = pack_bf16(y6, y7);
    xb_next[(size_t)row * 8 + q] = o;

    // acc = (acc_in + y) * scale  (f32); layer0 acc_in = x0 from sources
    size_t base = (size_t)row * 16 + q * 2;
    float4 a0, a1;
    if (layer0) {
        const float4* src = (row < N_USERS_C)
            ? x0u + (size_t)row * 16 + q * 2
            : x0i + (size_t)(row - N_USERS_C) * 16 + q * 2;
        a0 = src[0];
        a1 = src[1];
    } else {
        a0 = acc[base];
        a1 = acc[base + 1];
    }
    a0.x = (a0.x + y0) * scale;
    a0.y = (a0.y + y1) * scale;
    a0.z = (a0.z + y2) * scale;
    a0.w = (a0.w + y3) * scale;
    a1.x = (a1.x + y4) * scale;
    a1.y = (a1.y + y5) * scale;
    a1.z = (a1.z + y6) * scale;
    a1.w = (a1.w + y7) * scale;
    acc[base]     = a0;
    acc[base + 1] = a1;
}

// ---------------- fallback (R0 atomic path, f32) ----------------

__global__ void __launch_bounds__(256) init_concat_f32(
    const float4* __restrict__ user4,
    const float4* __restrict__ item4,
    float4* __restrict__ emb4,
    float4* __restrict__ acc4)
{
    int i = blockIdx.x * 256 + threadIdx.x;
    if (i >= TOT4) return;
    float4 v = (i < USER4) ? user4[i] : item4[i - USER4];
    emb4[i] = v;
    acc4[i] = v;
}

__global__ void __launch_bounds__(256) spmm_scatter(
    const int*   __restrict__ rows,
    const int*   __restrict__ cols,
    const float* __restrict__ vals,
    const float* __restrict__ x,
    float*       __restrict__ y)
{
    long long tid = (long long)blockIdx.x * 256 + threadIdx.x;
    int e = (int)(tid >> 4);
    if (e >= NNZ_C) return;
    int q = (int)(tid & 15);
    int   r = rows[e];
    int   c = cols[e];
    float v = vals[e];
    float4 xv = ((const float4*)x)[c * 16 + q];
    float* yp = y + (long long)r * DIM + q * 4;
    atomicAdd(yp + 0, v * xv.x);
    atomicAdd(yp + 1, v * xv.y);
    atomicAdd(yp + 2, v * xv.z);
    atomicAdd(yp + 3, v * xv.w);
}

__global__ void __launch_bounds__(256) acc_add(
    const float4* __restrict__ nxt, float4* __restrict__ acc, float scale)
{
    int i = blockIdx.x * 256 + threadIdx.x;
    if (i >= TOT4) return;
    float4 a = acc[i];
    float4 n = nxt[i];
    a.x = (a.x + n.x) * scale;
    a.y = (a.y + n.y) * scale;
    a.z = (a.z + n.z) * scale;
    a.w = (a.w + n.w) * scale;
    acc[i] = a;
}

// ---------------- launch ----------------

extern "C" void kernel_launch(void* const* d_in, const int* in_sizes, int n_in,
                              void* d_out, int out_size, void* d_ws, size_t ws_size,
                              hipStream_t stream)
{
    const int*   rows = (const int*)  d_in[0];
    const int*   cols = (const int*)  d_in[1];
    const float* vals = (const float*)d_in[2];
    const float* uemb = (const float*)d_in[3];
    const float* iemb = (const float*)d_in[4];
    float*       out  = (float*)d_out;

    const size_t embBytes   = (size_t)N_NODES_C * DIM * sizeof(float);   // 76.8 MB
    const size_t bfBytes    = (size_t)N_NODES_C * DIM * 2;               // 38.4 MB
    const size_t edgeBytes  = (size_t)NNZ_C * sizeof(int2);              // 76.8 MB
    const size_t padBytes   = (size_t)NBKT * CPAD * sizeof(int);         // 37.5 KB
    const size_t rsBytes    = (size_t)(N_NODES_C + 1) * sizeof(int);     // 1.2 MB

    char* w = (char*)d_ws;
    size_t off = 0;
    unsigned* xbf0   = (unsigned*)(w + off); off += bfBytes;
    unsigned* xbf1   = (unsigned*)(w + off); off += bfBytes;
    int2*  binned    = (int2*) (w + off); off += edgeBytes;
    int2*  binned2   = (int2*) (w + off); off += edgeBytes;
    int*   rowStart  = (int*)  (w + off); off += rsBytes;
    int*   countsP   = (int*)  (w + off); off += padBytes;
    int*   cursorP   = (int*)  (w + off); off += padBytes;
    int*   bstart    = (int*)  (w + off); off += (size_t)(NBKT + 1) * sizeof(int) + 4096;
    const size_t needed = off;   // ~232 MB

    const int gridE    = (TOT4 + 255) / 256;
    const int gridPull = (N_NODES_C * 8) / 256;   // 9375
    const int gridBin  = (NNZ_C + STAGE_T - 1) / STAGE_T;   // 1563

    if (ws_size >= needed) {
        init_concat_bf16<<<gridE, 256, 0, stream>>>(
            (const float4*)uemb, (const float4*)iemb, (uint2*)xbf0);

        hipMemsetAsync(countsP, 0, padBytes, stream);
        bucket_hist_lds<<<256, 1024, 0, stream>>>(rows, countsP);
        bucket_scan<<<1, 1024, 0, stream>>>(countsP, bstart, cursorP);
        bin_stage<<<gridBin, 1024, 0, stream>>>(rows, cols, vals, cursorP, binned);
        sort_bucket<<<NBKT, 1024, 0, stream>>>(binned, bstart, binned2, rowStart);

        unsigned* cur = xbf0;
        unsigned* nxt = xbf1;
        for (int layer = 0; layer < 3; ++layer) {
            float scale = (layer == 2) ? 0.25f : 1.0f;
            spmm_pull_bf16<<<gridPull, 256, 0, stream>>>(
                binned2, rowStart, (const uint4*)cur, (uint4*)nxt,
                (float4*)out, (const float4*)uemb, (const float4*)iemb,
                (layer == 0) ? 1 : 0, scale);
            unsigned* t = cur; cur = nxt; nxt = t;
        }
    } else {
        // fallback: atomic scatter path (needs only 2*embBytes)
        float* buf0 = (float*)d_ws;
        float* buf1 = (float*)((char*)d_ws + embBytes);
        init_concat_f32<<<gridE, 256, 0, stream>>>(
            (const float4*)uemb, (const float4*)iemb, (float4*)buf0, (float4*)out);
        const long long sThreads = (long long)NNZ_C * 16;
        const int gridS = (int)((sThreads + 255) / 256);
        float* cur = buf0;
        float* nxt = buf1;
        for (int layer = 0; layer < 3; ++layer) {
            hipMemsetAsync(nxt, 0, embBytes, stream);
            spmm_scatter<<<gridS, 256, 0, stream>>>(rows, cols, vals, cur, nxt);
            float scale = (layer == 2) ? 0.25f : 1.0f;
            acc_add<<<gridE, 256, 0, stream>>>((const float4*)nxt, (float4*)out, scale);
            float* t = cur; cur = nxt; nxt = t;
        }
    }
}